// Round 10
// baseline (166.382 us; speedup 1.0000x reference)
//
#include <hip/hip_runtime.h>

#define NN 40000
#define NPAD 40064
#define FF 128
#define EE 640000
#define CAP 64    // padded-CSR capacity; deg ~ Poisson(16), P(any > 64) ~ 1e-17
#define SENT NN   // sentinel neighbor id -> zeroed feature row

// Activation layouts:
//  - frag (MFMA operand): byte(r,k) = (r>>4)*4096 + (k>>3)*256 + (r&15)*16 + (k&7)*2
//  - gather source: TWO half buffers [NN+1][64] ushort (features 0-63 / 64-127).
//    Each gather half-dispatch touches a single 5.12MB buffer -> fits per-XCD L2
//    (4MB) at 78% vs 39% for the combined 10.25MB buffer (round-9 analysis:
//    gather is L2-capacity-miss bound, not latency bound).

typedef short s8v __attribute__((ext_vector_type(8)));   // 8 bf16 (4 VGPRs)
typedef float f4v __attribute__((ext_vector_type(4)));   // MFMA acc

__device__ __forceinline__ unsigned short f2bf(float f) {
    unsigned u = __float_as_uint(f);
    u += 0x7FFFu + ((u >> 16) & 1u);     // RNE
    return (unsigned short)(u >> 16);
}
__device__ __forceinline__ float bf2f(unsigned short h) {
    return __uint_as_float(((unsigned)h) << 16);
}

__device__ __forceinline__ int edge_at(const void* edges, int is64, long long pos) {
    return is64 ? (int)((const long long*)edges)[pos]
                : ((const int*)edges)[pos];
}

// ---------------- fused prep ----------------
// [0,10000): convert x -> XA/XB half rows + XfH/XfL frags
// [10000,11250): fill pcsr with SENT; [11250,11290): zero cnt
// 11290: dtype sniff; 11291: zero sentinel rows XA/XB/H1A/H1B
// [11292,11449): init out = bfc; [11449,11513): prepw W images
#define PREP_CONV 10000
#define PREP_PF   10000
#define PREP_ZC   11250
#define PREP_DET  11290
#define PREP_ZR   11291
#define PREP_OI   11292
#define PREP_W    11449
#define PREP_TOT  11513
__global__ __launch_bounds__(256) void prep_kernel(const float* __restrict__ x,
        const int* __restrict__ e32,
        const float* __restrict__ W1l, const float* __restrict__ W1r,
        const float* __restrict__ W2l, const float* __restrict__ W2r,
        const float* __restrict__ bfc,
        int* __restrict__ cnt, int* __restrict__ flag,
        unsigned short* __restrict__ pcsr,
        unsigned short* __restrict__ XA, unsigned short* __restrict__ XB,
        unsigned short* __restrict__ XfH, unsigned short* __restrict__ XfL,
        unsigned short* __restrict__ H1A, unsigned short* __restrict__ H1B,
        unsigned short* __restrict__ Wimg, float* __restrict__ out) {
    int bid = blockIdx.x, tid = threadIdx.x;
    if (bid < PREP_CONV) {
        int r = (bid * 256 + tid) >> 6;
        if (r >= NN) return;
        int lane = tid & 63;
        float2 v = *(const float2*)&x[r * FF + 2 * lane];
        ushort2 hi, lo;
        hi.x = f2bf(v.x); lo.x = f2bf(v.x - bf2f(hi.x));
        hi.y = f2bf(v.y); lo.y = f2bf(v.y - bf2f(hi.y));
        if (lane < 32) *(ushort2*)&XA[r * 64 + 2 * lane] = hi;
        else           *(ushort2*)&XB[r * 64 + 2 * lane - 64] = hi;
        size_t fo = (size_t)(r >> 4) * 4096 + (size_t)(lane >> 2) * 256
                  + (r & 15) * 16 + (lane & 3) * 4;
        *(ushort2*)((char*)XfH + fo) = hi;
        *(ushort2*)((char*)XfL + fo) = lo;
    } else if (bid < PREP_ZC) {
        int t = (bid - PREP_PF) * 256 + tid;   // 320000 x 16B = whole pcsr
        const int sv = (SENT << 16) | SENT;
        int4 s4 = {sv, sv, sv, sv};
        ((int4*)pcsr)[t] = s4;
    } else if (bid < PREP_DET) {
        int t = (bid - PREP_ZC) * 256 + tid;
        if (t * 4 < NPAD) {
            int4 z = {0, 0, 0, 0};
            *(int4*)&cnt[t * 4] = z;
        }
    } else if (bid == PREP_DET) {
        if (tid < 64) {
            int v = e32[2 * tid + 1];
            unsigned long long b = __ballot(v != 0);
            if (tid == 0) *flag = (b == 0ULL) ? 1 : 0;   // 1 => int64 layout
        }
    } else if (bid == PREP_ZR) {
        if (tid < 32)       ((int*)(XA  + SENT * 64))[tid] = 0;
        else if (tid < 64)  ((int*)(XB  + SENT * 64))[tid - 32] = 0;
        else if (tid < 96)  ((int*)(H1A + SENT * 64))[tid - 64] = 0;
        else if (tid < 128) ((int*)(H1B + SENT * 64))[tid - 96] = 0;
    } else if (bid < PREP_W) {
        int i = (bid - PREP_OI) * 256 + tid;   // 157 blocks (round-7 lesson: full NN)
        if (i < NN) *(float2*)&out[i * 2] = make_float2(bfc[0], bfc[1]);
    } else {
        // prepw: pre-swizzled LDS W image. Per layer L, col-half h (64KB):
        // byte = L*131072 + h*65536 + c*16384 + n*256 + ((2k)^((n&7)<<4))
        int wid = (bid - PREP_W) * 256 + tid;   // 64 blocks -> 16384 items
        int m = wid & 15;
        int n = (wid >> 4) & 63;
        int c = (wid >> 10) & 3;
        int h = (wid >> 12) & 1;
        int L = wid >> 13;
        const float* M = (L == 0) ? ((c < 2) ? W1l : W1r) : ((c < 2) ? W2l : W2r);
        int col = h * 64 + n;
        unsigned short o[8];
#pragma unroll
        for (int i2 = 0; i2 < 8; i2++) {
            float v = M[(m * 8 + i2) * FF + col];
            unsigned short hi = f2bf(v);
            o[i2] = (c & 1) ? f2bf(v - bf2f(hi)) : hi;
        }
        size_t byteoff = (size_t)L * 131072 + (size_t)h * 65536 + c * 16384 + n * 256
                       + (unsigned)((m * 16) ^ ((n & 7) << 4));
        *(s8v*)((char*)Wimg + byteoff) = *(const s8v*)o;
    }
}

// ---------------- single-pass padded-CSR fill (8 edges/thread) ----------------
__global__ __launch_bounds__(256) void fillp_kernel(const void* __restrict__ edges,
        const int* __restrict__ flag, int* __restrict__ cnt,
        unsigned short* __restrict__ pcsr) {
    int t = blockIdx.x * 256 + threadIdx.x;   // 80000 threads, 8 edges each
    long long e0 = (long long)t * 8;
    if (e0 >= EE) return;
    int is64 = *flag;
    int s[8], d[8], p[8];
#pragma unroll
    for (int i = 0; i < 8; i++) {
        s[i] = edge_at(edges, is64, e0 + i);
        d[i] = edge_at(edges, is64, (long long)EE + e0 + i);
    }
#pragma unroll
    for (int i = 0; i < 8; i++) p[i] = atomicAdd(&cnt[d[i]], 1);
#pragma unroll
    for (int i = 0; i < 8; i++)
        if (p[i] < CAP) pcsr[d[i] * CAP + p[i]] = (unsigned short)s[i];
}

// ---------------- half-gather: mean over neighbor rows of ONE feature half ----------------
// Wave per node; lane owns feature k = lane (+64 for HALF=1). Source is a 5.12MB
// [NN+1][64] buffer -> near-fits per-XCD L2. Neighbor count rounded to x8 via
// SENT padding (zero rows). Per-feature accumulation order identical to the
// full gather -> bit-identical output.
template<int HALF>
__global__ __launch_bounds__(256) void gather_half(const unsigned short* __restrict__ pcsr,
        const int* __restrict__ cnt,
        const unsigned short* __restrict__ H,
        unsigned short* __restrict__ AfH, unsigned short* __restrict__ AfL) {
    int wid = (blockIdx.x * 256 + threadIdx.x) >> 6;   // node id
    int lane = threadIdx.x & 63;
    if (wid >= NN) return;
    int deg = cnt[wid];
    int nd = min(deg, CAP);
    int ndr = (nd + 7) & ~7;                 // pad slots hold SENT (zero row)
    int idx = (int)pcsr[wid * CAP + lane];   // one coalesced 128B load
    float a = 0.f;
    for (int j = 0; j < ndr; j += 8) {
        int s[8];
#pragma unroll
        for (int u = 0; u < 8; ++u) s[u] = __shfl(idx, j + u);
        unsigned short v[8];
#pragma unroll
        for (int u = 0; u < 8; ++u) v[u] = H[s[u] * 64 + lane];
#pragma unroll
        for (int u = 0; u < 8; ++u) a += bf2f(v[u]);
    }
    a *= 1.0f / fmaxf((float)deg, 1.0f);
    unsigned short hi = f2bf(a);
    unsigned short lo = f2bf(a - bf2f(hi));
    int k = lane + HALF * 64;
    size_t fo = (size_t)(wid >> 4) * 4096 + (size_t)(k >> 3) * 256
              + (wid & 15) * 16 + (k & 7) * 2;
    *(unsigned short*)((char*)AfH + fo) = hi;
    *(unsigned short*)((char*)AfL + fo) = lo;
}

// ---------------- split-bf16 MFMA dual-GEMM, frag-ordered operands ----------------
// out = relu( A@Wl + bias + X@Wr ), product = hi*hi + lo*hi + hi*lo per pair.
// LAYER 0: write H1A/H1B half rows (hi) + H1f hi/lo frags. LAYER 1: fused FC head.
template<int LAYER>
__global__ __launch_bounds__(256, 2) void gemm_mfma(
        const unsigned short* __restrict__ AfH, const unsigned short* __restrict__ AfL,
        const unsigned short* __restrict__ XfH, const unsigned short* __restrict__ XfL,
        const unsigned short* __restrict__ Wimg, const float* __restrict__ bias,
        unsigned short* __restrict__ H1A, unsigned short* __restrict__ H1B,
        unsigned short* __restrict__ H1fH, unsigned short* __restrict__ H1fL,
        const float* __restrict__ Wfc, float* __restrict__ out) {
    __shared__ unsigned short WL[32768];   // 64KB
    int tid = threadIdx.x;
    int rb = blockIdx.x >> 1, half = blockIdx.x & 1;

    {
        const int4* gs = (const int4*)((const char*)Wimg + half * 65536) + tid;
        int4* ls = (int4*)WL + tid;
#pragma unroll
        for (int it = 0; it < 16; ++it) ls[it * 256] = gs[it * 256];
    }
    __syncthreads();

    int wid = tid >> 6, lane = tid & 63;
    int g = lane >> 4, c16 = lane & 15;
    int rbase = rb * 128 + wid * 32;
    int swz = (c16 & 7) << 4;

    f4v acc[2][4];
#pragma unroll
    for (int i = 0; i < 2; i++)
#pragma unroll
        for (int j = 0; j < 4; j++) acc[i][j] = (f4v){0.f, 0.f, 0.f, 0.f};

    size_t b0 = (size_t)(rbase >> 4) * 4096 + lane * 16;
    size_t b1 = b0 + 4096;

#pragma unroll
    for (int ch = 0; ch < 4; ++ch) {
        size_t o0 = b0 + ch * 1024, o1 = b1 + ch * 1024;
        s8v fa0h = *(const s8v*)((const char*)AfH + o0);
        s8v fa0l = *(const s8v*)((const char*)AfL + o0);
        s8v fx0h = *(const s8v*)((const char*)XfH + o0);
        s8v fx0l = *(const s8v*)((const char*)XfL + o0);
        s8v fa1h = *(const s8v*)((const char*)AfH + o1);
        s8v fa1l = *(const s8v*)((const char*)AfL + o1);
        s8v fx1h = *(const s8v*)((const char*)XfH + o1);
        s8v fx1l = *(const s8v*)((const char*)XfL + o1);
        int kaddr = ((ch * 4 + g) * 16) ^ swz;
#pragma unroll
        for (int nt = 0; nt < 4; ++nt) {
            const char* wb = (const char*)WL + (nt * 16 + c16) * 256 + kaddr;
            s8v wlh = *(const s8v*)(wb);
            s8v wll = *(const s8v*)(wb + 16384);
            s8v wrh = *(const s8v*)(wb + 32768);
            s8v wrl = *(const s8v*)(wb + 49152);
            acc[0][nt] = __builtin_amdgcn_mfma_f32_16x16x32_bf16(fa0h, wlh, acc[0][nt], 0, 0, 0);
            acc[0][nt] = __builtin_amdgcn_mfma_f32_16x16x32_bf16(fa0l, wlh, acc[0][nt], 0, 0, 0);
            acc[0][nt] = __builtin_amdgcn_mfma_f32_16x16x32_bf16(fa0h, wll, acc[0][nt], 0, 0, 0);
            acc[0][nt] = __builtin_amdgcn_mfma_f32_16x16x32_bf16(fx0h, wrh, acc[0][nt], 0, 0, 0);
            acc[0][nt] = __builtin_amdgcn_mfma_f32_16x16x32_bf16(fx0l, wrh, acc[0][nt], 0, 0, 0);
            acc[0][nt] = __builtin_amdgcn_mfma_f32_16x16x32_bf16(fx0h, wrl, acc[0][nt], 0, 0, 0);
            acc[1][nt] = __builtin_amdgcn_mfma_f32_16x16x32_bf16(fa1h, wlh, acc[1][nt], 0, 0, 0);
            acc[1][nt] = __builtin_amdgcn_mfma_f32_16x16x32_bf16(fa1l, wlh, acc[1][nt], 0, 0, 0);
            acc[1][nt] = __builtin_amdgcn_mfma_f32_16x16x32_bf16(fa1h, wll, acc[1][nt], 0, 0, 0);
            acc[1][nt] = __builtin_amdgcn_mfma_f32_16x16x32_bf16(fx1h, wrh, acc[1][nt], 0, 0, 0);
            acc[1][nt] = __builtin_amdgcn_mfma_f32_16x16x32_bf16(fx1l, wrh, acc[1][nt], 0, 0, 0);
            acc[1][nt] = __builtin_amdgcn_mfma_f32_16x16x32_bf16(fx1h, wrl, acc[1][nt], 0, 0, 0);
        }
    }

    // D layout (m89-verified): col = lane&15, row_in_tile = g*4 + reg
    int colb = half * 64 + c16;
    if (LAYER == 0) {
        unsigned short* Hrow = half ? H1B : H1A;
        float b4[4];
#pragma unroll
        for (int nt = 0; nt < 4; ++nt) b4[nt] = bias[colb + nt * 16];
#pragma unroll
        for (int rt = 0; rt < 2; ++rt)
#pragma unroll
            for (int j = 0; j < 4; ++j) {
                int r = rbase + rt * 16 + g * 4 + j;
                if (r < NN) {
                    size_t fragbase = (size_t)(r >> 4) * 4096 + (r & 15) * 16 + (c16 & 7) * 2;
#pragma unroll
                    for (int nt = 0; nt < 4; ++nt) {
                        float v = fmaxf(acc[rt][nt][j] + b4[nt], 0.f);
                        unsigned short hi = f2bf(v);
                        unsigned short lo = f2bf(v - bf2f(hi));
                        int k = colb + nt * 16;
                        Hrow[r * 64 + (c16 + nt * 16)] = hi;
                        size_t fo = fragbase + (size_t)(k >> 3) * 256;
                        *(unsigned short*)((char*)H1fH + fo) = hi;
                        *(unsigned short*)((char*)H1fL + fo) = lo;
                    }
                }
            }
    } else {
        float b4[4];
        float2 wf[4];
#pragma unroll
        for (int nt = 0; nt < 4; ++nt) {
            b4[nt] = bias[colb + nt * 16];
            wf[nt] = *(const float2*)&Wfc[(colb + nt * 16) * 2];
        }
#pragma unroll
        for (int rt = 0; rt < 2; ++rt)
#pragma unroll
            for (int j = 0; j < 4; ++j) {
                float q0 = 0.f, q1 = 0.f;
#pragma unroll
                for (int nt = 0; nt < 4; ++nt) {
                    float v = fmaxf(acc[rt][nt][j] + b4[nt], 0.f);
                    q0 += v * wf[nt].x;
                    q1 += v * wf[nt].y;
                }
#pragma unroll
                for (int m = 8; m >= 1; m >>= 1) {   // reduce over 16 lanes of group g
                    q0 += __shfl_xor(q0, m);
                    q1 += __shfl_xor(q1, m);
                }
                int r = rbase + rt * 16 + g * 4 + j;
                if (c16 == 0 && r < NN) {
                    atomicAdd(&out[r * 2 + 0], q0);
                    atomicAdd(&out[r * 2 + 1], q1);
                }
            }
    }
}

// ---------------- launch ----------------
extern "C" void kernel_launch(void* const* d_in, const int* in_sizes, int n_in,
                              void* d_out, int out_size, void* d_ws, size_t ws_size,
                              hipStream_t stream) {
    const float* x    = (const float*)d_in[0];
    const void* edges = d_in[1];
    const float* W1l  = (const float*)d_in[2];
    const float* b1   = (const float*)d_in[3];
    const float* W1r  = (const float*)d_in[4];
    const float* W2l  = (const float*)d_in[5];
    const float* b2   = (const float*)d_in[6];
    const float* W2r  = (const float*)d_in[7];
    const float* Wfc  = (const float*)d_in[8];
    const float* bfc  = (const float*)d_in[9];
    float* out = (float*)d_out;

    char* ws = (char*)d_ws;
    const size_t BUF  = 10256384;   // NPAD*128*2 (frag buffers)
    const size_t HBUF = 5120128;    // (NN+1)*64*2 (half row buffers)
    size_t off = 0;
    int* flag = (int*)(ws + off); off += 256;
    int* cnt  = (int*)(ws + off); off += 160256;
    unsigned short* pcsr = (unsigned short*)(ws + off); off += 5120000;
    unsigned short* AfH  = (unsigned short*)(ws + off); off += BUF;
    unsigned short* AfL  = (unsigned short*)(ws + off); off += BUF;
    unsigned short* XfH  = (unsigned short*)(ws + off); off += BUF;
    unsigned short* XfL  = (unsigned short*)(ws + off); off += BUF;
    unsigned short* H1fH = (unsigned short*)(ws + off); off += BUF;
    unsigned short* H1fL = (unsigned short*)(ws + off); off += BUF;
    unsigned short* XA   = (unsigned short*)(ws + off); off += HBUF;
    unsigned short* XB   = (unsigned short*)(ws + off); off += HBUF;
    unsigned short* H1A  = (unsigned short*)(ws + off); off += HBUF;
    unsigned short* H1B  = (unsigned short*)(ws + off); off += HBUF;
    unsigned short* Wimg = (unsigned short*)(ws + off); off += 262144;

    // 1. fused prep: convert + pcsr-sentinel + zero cnt + detect + zero rows
    //    + out-init + W images
    prep_kernel<<<PREP_TOT, 256, 0, stream>>>(x, (const int*)edges,
            W1l, W1r, W2l, W2r, bfc, cnt, flag, pcsr,
            XA, XB, XfH, XfL, H1A, H1B, Wimg, out);
    // 2. padded-CSR build
    fillp_kernel<<<(EE / 8 + 255) / 256, 256, 0, stream>>>(edges, flag, cnt, pcsr);
    // 3/4. layer-1 aggregate, one feature-half at a time (L2-capacity locality)
    gather_half<0><<<NN * 64 / 256, 256, 0, stream>>>(pcsr, cnt, XA, AfH, AfL);
    gather_half<1><<<NN * 64 / 256, 256, 0, stream>>>(pcsr, cnt, XB, AfH, AfL);
    // 5. layer-1 dual-GEMM
    gemm_mfma<0><<<(NPAD / 128) * 2, 256, 0, stream>>>(AfH, AfL, XfH, XfL,
            Wimg, b1, H1A, H1B, H1fH, H1fL, nullptr, nullptr);
    // 6/7. layer-2 aggregate halves
    gather_half<0><<<NN * 64 / 256, 256, 0, stream>>>(pcsr, cnt, H1A, AfH, AfL);
    gather_half<1><<<NN * 64 / 256, 256, 0, stream>>>(pcsr, cnt, H1B, AfH, AfL);
    // 8. layer-2 dual-GEMM + FC head
    gemm_mfma<1><<<(NPAD / 128) * 2, 256, 0, stream>>>(AfH, AfL, H1fH, H1fL,
            Wimg + 65536, b2, nullptr, nullptr, nullptr, nullptr, Wfc, out);
}

// Round 11
// 147.302 us; speedup vs baseline: 1.1295x; 1.1295x over previous
//
#include <hip/hip_runtime.h>

#define NN 40000
#define NPAD 40064
#define FF 128
#define EE 640000
#define CAP 64    // padded-CSR capacity; deg ~ Poisson(16), P(any > 64) ~ 1e-17
#define SENT NN   // sentinel neighbor id -> zeroed feature row

// Round-11 = round-9 structure (best measured, 147us) + out-init folded into
// prep (validated bit-exact in round 10). Round-10's feature-half split is
// REVERTED: the miss unit is the cache line, so half-rows doubled the random
// row-touch count (1.28M vs 640K) without halving traffic -> +19us.

typedef short s8v __attribute__((ext_vector_type(8)));   // 8 bf16 (4 VGPRs)
typedef float f4v __attribute__((ext_vector_type(4)));   // MFMA acc

__device__ __forceinline__ unsigned short f2bf(float f) {
    unsigned u = __float_as_uint(f);
    u += 0x7FFFu + ((u >> 16) & 1u);     // RNE
    return (unsigned short)(u >> 16);
}
__device__ __forceinline__ float bf2f(unsigned short h) {
    return __uint_as_float(((unsigned)h) << 16);
}

__device__ __forceinline__ int edge_at(const void* edges, int is64, long long pos) {
    return is64 ? (int)((const long long*)edges)[pos]
                : ((const int*)edges)[pos];
}

// ---------------- fused prep ----------------
// [0,10000): convert x -> XrowH + XfH/XfL frags
// [10000,11250): fill pcsr with SENT; [11250,11290): zero cnt
// 11290: dtype sniff; 11291: zero sentinel rows of XrowH & H1row
// [11292,11449): init out = bfc; [11449,11513): prepw W images
#define PREP_CONV 10000
#define PREP_PF   10000
#define PREP_ZC   11250
#define PREP_DET  11290
#define PREP_ZR   11291
#define PREP_OI   11292
#define PREP_W    11449
#define PREP_TOT  11513
__global__ __launch_bounds__(256) void prep_kernel(const float* __restrict__ x,
        const int* __restrict__ e32,
        const float* __restrict__ W1l, const float* __restrict__ W1r,
        const float* __restrict__ W2l, const float* __restrict__ W2r,
        const float* __restrict__ bfc,
        int* __restrict__ cnt, int* __restrict__ flag,
        unsigned short* __restrict__ pcsr,
        unsigned short* __restrict__ XrowH,
        unsigned short* __restrict__ XfH, unsigned short* __restrict__ XfL,
        unsigned short* __restrict__ H1row,
        unsigned short* __restrict__ Wimg, float* __restrict__ out) {
    int bid = blockIdx.x, tid = threadIdx.x;
    if (bid < PREP_CONV) {
        int r = (bid * 256 + tid) >> 6;
        if (r >= NN) return;
        int lane = tid & 63;
        float2 v = *(const float2*)&x[r * FF + 2 * lane];
        ushort2 hi, lo;
        hi.x = f2bf(v.x); lo.x = f2bf(v.x - bf2f(hi.x));
        hi.y = f2bf(v.y); lo.y = f2bf(v.y - bf2f(hi.y));
        *(ushort2*)&XrowH[r * FF + 2 * lane] = hi;
        size_t fo = (size_t)(r >> 4) * 4096 + (size_t)(lane >> 2) * 256
                  + (r & 15) * 16 + (lane & 3) * 4;
        *(ushort2*)((char*)XfH + fo) = hi;
        *(ushort2*)((char*)XfL + fo) = lo;
    } else if (bid < PREP_ZC) {
        int t = (bid - PREP_PF) * 256 + tid;   // 320000 x 16B = whole pcsr
        const int sv = (SENT << 16) | SENT;
        int4 s4 = {sv, sv, sv, sv};
        ((int4*)pcsr)[t] = s4;
    } else if (bid < PREP_DET) {
        int t = (bid - PREP_ZC) * 256 + tid;
        if (t * 4 < NPAD) {
            int4 z = {0, 0, 0, 0};
            *(int4*)&cnt[t * 4] = z;
        }
    } else if (bid == PREP_DET) {
        if (tid < 64) {
            int v = e32[2 * tid + 1];
            unsigned long long b = __ballot(v != 0);
            if (tid == 0) *flag = (b == 0ULL) ? 1 : 0;   // 1 => int64 layout
        }
    } else if (bid == PREP_ZR) {
        if (tid < 64)       ((int*)(XrowH + SENT * FF))[tid] = 0;
        else if (tid < 128) ((int*)(H1row + SENT * FF))[tid - 64] = 0;
    } else if (bid < PREP_W) {
        int i = (bid - PREP_OI) * 256 + tid;   // 157 blocks: full NN (round-7 lesson)
        if (i < NN) *(float2*)&out[i * 2] = make_float2(bfc[0], bfc[1]);
    } else {
        // prepw: pre-swizzled LDS W image. Per layer L, col-half h (64KB):
        // byte = L*131072 + h*65536 + c*16384 + n*256 + ((2k)^((n&7)<<4))
        int wid = (bid - PREP_W) * 256 + tid;   // 64 blocks -> 16384 items
        int m = wid & 15;
        int n = (wid >> 4) & 63;
        int c = (wid >> 10) & 3;
        int h = (wid >> 12) & 1;
        int L = wid >> 13;
        const float* M = (L == 0) ? ((c < 2) ? W1l : W1r) : ((c < 2) ? W2l : W2r);
        int col = h * 64 + n;
        unsigned short o[8];
#pragma unroll
        for (int i2 = 0; i2 < 8; i2++) {
            float v = M[(m * 8 + i2) * FF + col];
            unsigned short hi = f2bf(v);
            o[i2] = (c & 1) ? f2bf(v - bf2f(hi)) : hi;
        }
        size_t byteoff = (size_t)L * 131072 + (size_t)h * 65536 + c * 16384 + n * 256
                       + (unsigned)((m * 16) ^ ((n & 7) << 4));
        *(s8v*)((char*)Wimg + byteoff) = *(const s8v*)o;
    }
}

// ---------------- single-pass padded-CSR fill (8 edges/thread) ----------------
__global__ __launch_bounds__(256) void fillp_kernel(const void* __restrict__ edges,
        const int* __restrict__ flag, int* __restrict__ cnt,
        unsigned short* __restrict__ pcsr) {
    int t = blockIdx.x * 256 + threadIdx.x;   // 80000 threads, 8 edges each
    long long e0 = (long long)t * 8;
    if (e0 >= EE) return;
    int is64 = *flag;
    int s[8], d[8], p[8];
#pragma unroll
    for (int i = 0; i < 8; i++) {
        s[i] = edge_at(edges, is64, e0 + i);
        d[i] = edge_at(edges, is64, (long long)EE + e0 + i);
    }
#pragma unroll
    for (int i = 0; i < 8; i++) p[i] = atomicAdd(&cnt[d[i]], 1);
#pragma unroll
    for (int i = 0; i < 8; i++)
        if (p[i] < CAP) pcsr[d[i] * CAP + p[i]] = (unsigned short)s[i];
}

// ---------------- gather: mean over neighbor rows (hi-only), emit frag hi/lo ----------------
// Wave per node; lane owns feats [2*lane,2*lane+1]. Neighbor count rounded up to
// multiple of 8 via SENT padding (zero rows) -> uniform loop, 8 loads in flight.
__global__ __launch_bounds__(256) void gather_kernel(const unsigned short* __restrict__ pcsr,
        const int* __restrict__ cnt,
        const unsigned short* __restrict__ HrowH,
        unsigned short* __restrict__ AfH, unsigned short* __restrict__ AfL) {
    int wid = (blockIdx.x * 256 + threadIdx.x) >> 6;   // node id
    int lane = threadIdx.x & 63;
    if (wid >= NN) return;
    int deg = cnt[wid];
    int nd = min(deg, CAP);
    int ndr = (nd + 7) & ~7;                 // multiple of 8; pad slots hold SENT
    int idx = (int)pcsr[wid * CAP + lane];   // one coalesced 128B load
    const ushort2* Hp = (const ushort2*)HrowH;
    float ax = 0.f, ay = 0.f;
    for (int j = 0; j < ndr; j += 8) {
        int s[8];
#pragma unroll
        for (int u = 0; u < 8; ++u) s[u] = __shfl(idx, j + u);
        ushort2 v[8];
#pragma unroll
        for (int u = 0; u < 8; ++u) v[u] = Hp[s[u] * 64 + lane];
#pragma unroll
        for (int u = 0; u < 8; ++u) { ax += bf2f(v[u].x); ay += bf2f(v[u].y); }
    }
    float rd = 1.0f / fmaxf((float)deg, 1.0f);
    ax *= rd; ay *= rd;
    ushort2 hi, lo;
    hi.x = f2bf(ax); lo.x = f2bf(ax - bf2f(hi.x));
    hi.y = f2bf(ay); lo.y = f2bf(ay - bf2f(hi.y));
    size_t fo = (size_t)(wid >> 4) * 4096 + (size_t)(lane >> 2) * 256
              + (wid & 15) * 16 + (lane & 3) * 4;
    *(ushort2*)((char*)AfH + fo) = hi;
    *(ushort2*)((char*)AfL + fo) = lo;
}

// ---------------- split-bf16 MFMA dual-GEMM, frag-ordered operands ----------------
template<int LAYER>
__global__ __launch_bounds__(256, 2) void gemm_mfma(
        const unsigned short* __restrict__ AfH, const unsigned short* __restrict__ AfL,
        const unsigned short* __restrict__ XfH, const unsigned short* __restrict__ XfL,
        const unsigned short* __restrict__ Wimg, const float* __restrict__ bias,
        unsigned short* __restrict__ H1row,
        unsigned short* __restrict__ H1fH, unsigned short* __restrict__ H1fL,
        const float* __restrict__ Wfc, float* __restrict__ out) {
    __shared__ unsigned short WL[32768];   // 64KB
    int tid = threadIdx.x;
    int rb = blockIdx.x >> 1, half = blockIdx.x & 1;

    {
        const int4* gs = (const int4*)((const char*)Wimg + half * 65536) + tid;
        int4* ls = (int4*)WL + tid;
#pragma unroll
        for (int it = 0; it < 16; ++it) ls[it * 256] = gs[it * 256];
    }
    __syncthreads();

    int wid = tid >> 6, lane = tid & 63;
    int g = lane >> 4, c16 = lane & 15;
    int rbase = rb * 128 + wid * 32;
    int swz = (c16 & 7) << 4;

    f4v acc[2][4];
#pragma unroll
    for (int i = 0; i < 2; i++)
#pragma unroll
        for (int j = 0; j < 4; j++) acc[i][j] = (f4v){0.f, 0.f, 0.f, 0.f};

    size_t b0 = (size_t)(rbase >> 4) * 4096 + lane * 16;
    size_t b1 = b0 + 4096;

#pragma unroll
    for (int ch = 0; ch < 4; ++ch) {
        size_t o0 = b0 + ch * 1024, o1 = b1 + ch * 1024;
        s8v fa0h = *(const s8v*)((const char*)AfH + o0);
        s8v fa0l = *(const s8v*)((const char*)AfL + o0);
        s8v fx0h = *(const s8v*)((const char*)XfH + o0);
        s8v fx0l = *(const s8v*)((const char*)XfL + o0);
        s8v fa1h = *(const s8v*)((const char*)AfH + o1);
        s8v fa1l = *(const s8v*)((const char*)AfL + o1);
        s8v fx1h = *(const s8v*)((const char*)XfH + o1);
        s8v fx1l = *(const s8v*)((const char*)XfL + o1);
        int kaddr = ((ch * 4 + g) * 16) ^ swz;
#pragma unroll
        for (int nt = 0; nt < 4; ++nt) {
            const char* wb = (const char*)WL + (nt * 16 + c16) * 256 + kaddr;
            s8v wlh = *(const s8v*)(wb);
            s8v wll = *(const s8v*)(wb + 16384);
            s8v wrh = *(const s8v*)(wb + 32768);
            s8v wrl = *(const s8v*)(wb + 49152);
            acc[0][nt] = __builtin_amdgcn_mfma_f32_16x16x32_bf16(fa0h, wlh, acc[0][nt], 0, 0, 0);
            acc[0][nt] = __builtin_amdgcn_mfma_f32_16x16x32_bf16(fa0l, wlh, acc[0][nt], 0, 0, 0);
            acc[0][nt] = __builtin_amdgcn_mfma_f32_16x16x32_bf16(fa0h, wll, acc[0][nt], 0, 0, 0);
            acc[0][nt] = __builtin_amdgcn_mfma_f32_16x16x32_bf16(fx0h, wrh, acc[0][nt], 0, 0, 0);
            acc[0][nt] = __builtin_amdgcn_mfma_f32_16x16x32_bf16(fx0l, wrh, acc[0][nt], 0, 0, 0);
            acc[0][nt] = __builtin_amdgcn_mfma_f32_16x16x32_bf16(fx0h, wrl, acc[0][nt], 0, 0, 0);
            acc[1][nt] = __builtin_amdgcn_mfma_f32_16x16x32_bf16(fa1h, wlh, acc[1][nt], 0, 0, 0);
            acc[1][nt] = __builtin_amdgcn_mfma_f32_16x16x32_bf16(fa1l, wlh, acc[1][nt], 0, 0, 0);
            acc[1][nt] = __builtin_amdgcn_mfma_f32_16x16x32_bf16(fa1h, wll, acc[1][nt], 0, 0, 0);
            acc[1][nt] = __builtin_amdgcn_mfma_f32_16x16x32_bf16(fx1h, wrh, acc[1][nt], 0, 0, 0);
            acc[1][nt] = __builtin_amdgcn_mfma_f32_16x16x32_bf16(fx1l, wrh, acc[1][nt], 0, 0, 0);
            acc[1][nt] = __builtin_amdgcn_mfma_f32_16x16x32_bf16(fx1h, wrl, acc[1][nt], 0, 0, 0);
        }
    }

    // D layout (m89-verified): col = lane&15, row_in_tile = g*4 + reg
    int colb = half * 64 + c16;
    if (LAYER == 0) {
        float b4[4];
#pragma unroll
        for (int nt = 0; nt < 4; ++nt) b4[nt] = bias[colb + nt * 16];
#pragma unroll
        for (int rt = 0; rt < 2; ++rt)
#pragma unroll
            for (int j = 0; j < 4; ++j) {
                int r = rbase + rt * 16 + g * 4 + j;
                if (r < NN) {
                    size_t fragbase = (size_t)(r >> 4) * 4096 + (r & 15) * 16 + (c16 & 7) * 2;
#pragma unroll
                    for (int nt = 0; nt < 4; ++nt) {
                        float v = fmaxf(acc[rt][nt][j] + b4[nt], 0.f);
                        unsigned short hi = f2bf(v);
                        unsigned short lo = f2bf(v - bf2f(hi));
                        int k = colb + nt * 16;
                        H1row[r * FF + k] = hi;
                        size_t fo = fragbase + (size_t)(k >> 3) * 256;
                        *(unsigned short*)((char*)H1fH + fo) = hi;
                        *(unsigned short*)((char*)H1fL + fo) = lo;
                    }
                }
            }
    } else {
        float b4[4];
        float2 wf[4];
#pragma unroll
        for (int nt = 0; nt < 4; ++nt) {
            b4[nt] = bias[colb + nt * 16];
            wf[nt] = *(const float2*)&Wfc[(colb + nt * 16) * 2];
        }
#pragma unroll
        for (int rt = 0; rt < 2; ++rt)
#pragma unroll
            for (int j = 0; j < 4; ++j) {
                float q0 = 0.f, q1 = 0.f;
#pragma unroll
                for (int nt = 0; nt < 4; ++nt) {
                    float v = fmaxf(acc[rt][nt][j] + b4[nt], 0.f);
                    q0 += v * wf[nt].x;
                    q1 += v * wf[nt].y;
                }
#pragma unroll
                for (int m = 8; m >= 1; m >>= 1) {   // reduce over 16 lanes of group g
                    q0 += __shfl_xor(q0, m);
                    q1 += __shfl_xor(q1, m);
                }
                int r = rbase + rt * 16 + g * 4 + j;
                if (c16 == 0 && r < NN) {
                    atomicAdd(&out[r * 2 + 0], q0);
                    atomicAdd(&out[r * 2 + 1], q1);
                }
            }
    }
}

// ---------------- launch ----------------
extern "C" void kernel_launch(void* const* d_in, const int* in_sizes, int n_in,
                              void* d_out, int out_size, void* d_ws, size_t ws_size,
                              hipStream_t stream) {
    const float* x    = (const float*)d_in[0];
    const void* edges = d_in[1];
    const float* W1l  = (const float*)d_in[2];
    const float* b1   = (const float*)d_in[3];
    const float* W1r  = (const float*)d_in[4];
    const float* W2l  = (const float*)d_in[5];
    const float* b2   = (const float*)d_in[6];
    const float* W2r  = (const float*)d_in[7];
    const float* Wfc  = (const float*)d_in[8];
    const float* bfc  = (const float*)d_in[9];
    float* out = (float*)d_out;

    char* ws = (char*)d_ws;
    const size_t BUF = 10256384;   // NPAD*128*2
    size_t off = 0;
    int* flag = (int*)(ws + off); off += 256;
    int* cnt  = (int*)(ws + off); off += 160256;
    unsigned short* pcsr  = (unsigned short*)(ws + off); off += 5120000;
    unsigned short* AfH   = (unsigned short*)(ws + off); off += BUF;
    unsigned short* AfL   = (unsigned short*)(ws + off); off += BUF;
    unsigned short* XfH   = (unsigned short*)(ws + off); off += BUF;
    unsigned short* XfL   = (unsigned short*)(ws + off); off += BUF;
    unsigned short* XrowH = (unsigned short*)(ws + off); off += BUF;
    unsigned short* H1fH  = (unsigned short*)(ws + off); off += BUF;
    unsigned short* H1fL  = (unsigned short*)(ws + off); off += BUF;
    unsigned short* H1row = (unsigned short*)(ws + off); off += BUF;
    unsigned short* Wimg  = (unsigned short*)(ws + off); off += 262144;

    // 1. fused prep: convert + pcsr-sentinel + zero cnt + detect + zero rows
    //    + out-init + W images
    prep_kernel<<<PREP_TOT, 256, 0, stream>>>(x, (const int*)edges,
            W1l, W1r, W2l, W2r, bfc, cnt, flag, pcsr,
            XrowH, XfH, XfL, H1row, Wimg, out);
    // 2. padded-CSR build (8 edges/thread)
    fillp_kernel<<<(EE / 8 + 255) / 256, 256, 0, stream>>>(edges, flag, cnt, pcsr);
    // 3. layer-1 aggregate
    gather_kernel<<<NN * 64 / 256, 256, 0, stream>>>(pcsr, cnt, XrowH, AfH, AfL);
    // 4. layer-1 dual-GEMM
    gemm_mfma<0><<<(NPAD / 128) * 2, 256, 0, stream>>>(AfH, AfL, XfH, XfL,
            Wimg, b1, H1row, H1fH, H1fL, nullptr, nullptr);
    // 5. layer-2 aggregate
    gather_kernel<<<NN * 64 / 256, 256, 0, stream>>>(pcsr, cnt, H1row, AfH, AfL);
    // 6. layer-2 dual-GEMM + FC head
    gemm_mfma<1><<<(NPAD / 128) * 2, 256, 0, stream>>>(AfH, AfL, H1fH, H1fL,
            Wimg + 65536, b2, nullptr, nullptr, nullptr, Wfc, out);
}